// Round 14
// baseline (448.657 us; speedup 1.0000x reference)
//
#include <hip/hip_runtime.h>
#include <stdint.h>
#include <stddef.h>

// ---------------- problem constants ----------------
#define T_TOK  8192        // B*S tokens
#define DIMK   1024        // model dim
#define INTERK 1024        // routed expert inter dim
#define NEXP   8
#define SINT   2048        // shared inter dim
#define CAP    18432       // 2*T + 8*256 padding capacity (slot rows, 256-aligned)
#define RT256  72          // CAP/256 row tiles (worst case)

#define NS1_R  16          // gemm1 routed N-slices (2*INTERK/128)
#define NS1_S  32          // gemm1 shared N-slices (2*SINT/128)
#define RT_S   32          // shared row tiles (T_TOK/256)
#define G1R    (NS1_R * RT256)          // 1152
#define G1     (G1R + NS1_S * RT_S)     // 2176
#define NS2    8           // gemm2 N-slices (DIMK/128)
#define G2R    (NS2 * RT256)            // 576
#define G2S    (NS2 * RT_S)             // 256

typedef float  f32x4  __attribute__((ext_vector_type(4)));
typedef short  bf16x8 __attribute__((ext_vector_type(8)));

typedef __attribute__((address_space(1))) const unsigned int gas_u32;
typedef __attribute__((address_space(3))) unsigned int las_u32;

__device__ __forceinline__ void gload16(const void* g, void* l) {
  __builtin_amdgcn_global_load_lds((gas_u32*)g, (las_u32*)l, 16, 0, 0);
}

__device__ __forceinline__ unsigned short f2b(float f) {   // f32 -> bf16 RNE
  unsigned int u = __float_as_uint(f);
  u = (u + 0x7FFFu + ((u >> 16) & 1u)) >> 16;
  return (unsigned short)u;
}
__device__ __forceinline__ float b2f(unsigned short h) {
  return __uint_as_float(((unsigned int)h) << 16);
}

// raw barrier with compile-time memory fences (no vmcnt/lgkmcnt drain)
__device__ __forceinline__ void barrier_nodrain() {
  asm volatile("" ::: "memory");
  __builtin_amdgcn_s_barrier();
  asm volatile("" ::: "memory");
}

// ------- merged: gate (+x->bf16 convert) AND all weight converts, one launch -------
// blocks [0, 2048): gate, 4 tokens/block (numerics identical to prior rounds)
// blocks [2048, 2048+30720): weight converts, range-decoded float4 chunks:
//   [0,2*N1C) w1/w3->w13r interleaved; [.,+2*N2C) ws1/ws3->w13s; [.,+N3C) w2; [.,+N4C) ws2
#define N1C 2097152   // NEXP*INTERK*(DIMK/4)
#define N2C 524288    // SINT*(DIMK/4)
#define N3C 2097152   // NEXP*DIMK*(INTERK/4)
#define N4C 524288    // DIMK*(SINT/4)
#define GATE_BLOCKS (T_TOK / 4)
#define WCVT_BLOCKS ((2*N1C + 2*N2C + N3C + N4C) / 256)   // 30720
__global__ __launch_bounds__(256) void cvtgate_kernel(
    const float* __restrict__ x, const float* __restrict__ gw, const float* __restrict__ gb,
    int* __restrict__ top_i, float* __restrict__ top_w, unsigned short* __restrict__ xb,
    const float4* __restrict__ w1, const float4* __restrict__ w3,
    const float4* __restrict__ ws1, const float4* __restrict__ ws3,
    const float4* __restrict__ w2, const float4* __restrict__ ws2,
    unsigned short* __restrict__ w13r, unsigned short* __restrict__ w13s,
    unsigned short* __restrict__ w2b, unsigned short* __restrict__ ws2b) {
  int bid = blockIdx.x;
  if (bid < GATE_BLOCKS) {
    int t    = bid * 4 + (threadIdx.x >> 6);
    int lane = threadIdx.x & 63;
    const float* xr = x + (size_t)t * DIMK;
    unsigned short* xo = xb + (size_t)t * DIMK;
    float acc[NEXP];
#pragma unroll
    for (int e = 0; e < NEXP; ++e) acc[e] = 0.f;
    for (int i = lane; i < DIMK; i += 64) {
      float xv = xr[i];
      xo[i] = f2b(xv);
#pragma unroll
      for (int e = 0; e < NEXP; ++e) acc[e] += xv * gw[e * DIMK + i];
    }
#pragma unroll
    for (int e = 0; e < NEXP; ++e) {
      float v = acc[e];
#pragma unroll
      for (int off = 32; off > 0; off >>= 1) v += __shfl_down(v, off, 64);
      acc[e] = v;
    }
    if (lane == 0) {
      float lg[NEXP];
#pragma unroll
      for (int e = 0; e < NEXP; ++e) lg[e] = acc[e] + gb[e];
      int i0 = 0;
#pragma unroll
      for (int e = 1; e < NEXP; ++e) if (lg[e] > lg[i0]) i0 = e;   // first index wins ties
      int i1 = (i0 == 0) ? 1 : 0;
#pragma unroll
      for (int e = 0; e < NEXP; ++e) if (e != i0 && lg[e] > lg[i1]) i1 = e;
      float mx = lg[i0], s = 0.f;
#pragma unroll
      for (int e = 0; e < NEXP; ++e) s += expf(lg[e] - mx);
      top_i[t * 2]     = i0;
      top_i[t * 2 + 1] = i1;
      top_w[t * 2]     = expf(lg[i0] - mx) / s;
      top_w[t * 2 + 1] = expf(lg[i1] - mx) / s;
    }
    return;
  }
  long long i = (long long)(bid - GATE_BLOCKS) * 256 + threadIdx.x;
  float4 v;
  unsigned short* dst;
  size_t didx;
  if (i < 2 * (long long)N1C) {
    int is3 = i >= N1C;
    int j = (int)(i - (long long)is3 * N1C);
    int r = j >> 8, kc = j & 255;
    int e = r >> 10, rr = r & 1023, g = rr >> 4;
    size_t dst_r = (size_t)e * (2 * INTERK) + g * 32 + (is3 ? 16 : 0) + (rr & 15);
    v = (is3 ? w3 : w1)[j];
    dst = w13r; didx = dst_r * 256 + kc;
  } else if ((i -= 2 * (long long)N1C) < 2 * (long long)N2C) {
    int is3 = i >= N2C;
    int j = (int)(i - (long long)is3 * N2C);
    int r = j >> 8, kc = j & 255;
    int g = r >> 4;
    size_t dst_r = (size_t)g * 32 + (is3 ? 16 : 0) + (r & 15);
    v = (is3 ? ws3 : ws1)[j];
    dst = w13s; didx = dst_r * 256 + kc;
  } else if ((i -= 2 * (long long)N2C) < (long long)N3C) {
    int j = (int)i;
    v = w2[j];
    dst = w2b; didx = (size_t)j;
  } else {
    int j = (int)(i - N3C);
    v = ws2[j];
    dst = ws2b; didx = (size_t)j;
  }
  ushort4 o;
  o.x = f2b(v.x); o.y = f2b(v.y); o.z = f2b(v.z); o.w = f2b(v.w);
  *reinterpret_cast<ushort4*>(&dst[didx * 4]) = o;
}

// ------- route_build: count + scan + slot-assign, deterministic; emits wslot -------
// wslot[p] = routing weight of the token occupying slot p (0 for pad slots).
__global__ __launch_bounds__(512) void route_build_kernel(
    const int* __restrict__ top_i, const float* __restrict__ top_w,
    int* __restrict__ order, float* __restrict__ wslot, int* __restrict__ poff_g) {
  __shared__ int cnt[NEXP][512];
  __shared__ int base[NEXP][512];
  __shared__ int totals[NEXP];
  __shared__ int poff_s[NEXP + 1];
  int tid = threadIdx.x;
  int lane = tid & 63, w = tid >> 6;
  const int t0 = tid * 16;

  int c[NEXP];
#pragma unroll
  for (int e = 0; e < NEXP; ++e) c[e] = 0;
  for (int j = 0; j < 16; ++j) {
    int e0 = top_i[(t0 + j) * 2];
    int e1 = top_i[(t0 + j) * 2 + 1];
#pragma unroll
    for (int e = 0; e < NEXP; ++e) c[e] += (e0 == e) + (e1 == e);
  }
#pragma unroll
  for (int e = 0; e < NEXP; ++e) cnt[e][tid] = c[e];
  __syncthreads();

  {
    int running = 0;
    for (int ch = 0; ch < 8; ++ch) {
      int v = cnt[w][ch * 64 + lane];
      int incl = v;
#pragma unroll
      for (int off = 1; off < 64; off <<= 1) {
        int u = __shfl_up(incl, off, 64);
        if (lane >= off) incl += u;
      }
      base[w][ch * 64 + lane] = running + incl - v;
      running += __shfl(incl, 63, 64);
    }
    if (lane == 0) totals[w] = running;
  }
  __syncthreads();

  if (tid == 0) {
    int off = 0;
#pragma unroll
    for (int e = 0; e < NEXP; ++e) {
      poff_s[e] = off;
      off += (totals[e] + 255) & ~255;
    }
    poff_s[NEXP] = off;
#pragma unroll
    for (int e = 0; e <= NEXP; ++e) poff_g[e] = poff_s[e];
  }
  __syncthreads();

  int cur[NEXP];
#pragma unroll
  for (int e = 0; e < NEXP; ++e) cur[e] = poff_s[e] + base[e][tid];
  for (int j = 0; j < 16; ++j) {
    int t = t0 + j;
#pragma unroll
    for (int k = 0; k < 2; ++k) {
      int ei = top_i[t * 2 + k];
      int p = 0;
#pragma unroll
      for (int e = 0; e < NEXP; ++e)
        if (ei == e) { p = cur[e]; cur[e] = p + 1; }
      order[p] = t;
      wslot[p] = top_w[t * 2 + k];
    }
  }

#pragma unroll
  for (int e = 0; e < NEXP; ++e) {
    int s = poff_s[e] + totals[e], en = poff_s[e + 1];
    for (int i = s + tid; i < en; i += 512) { order[i] = 0; wslot[i] = 0.f; }
  }
}

// ====== core round-8 GEMM body: BM=256, BN=128, BK=64, 512 thr (8 waves 4x2) ======
// Depth-2 prefetch, 3 LDS buffers (144 KB), counted vmcnt(6), one barrier per tile,
// loose compiler-scheduled body, setprio around MFMA clusters, XOR-swizzled LDS.
// EPI 0: paired swiglu -> bf16 (interleaved w1/w3 B), real cols = 64/block-slice
// EPI 2: bias -> f32 store
// EPI 3: atomic combine: atomicAdd(out[order[row]*ldo+col], wslot[row]*(acc+bias))
#define A_ELE   16384   // 256*64 elements per A buffer
#define B_ELE   8192    // 128*64 elements per B buffer
#define BUF_ELE (A_ELE + B_ELE)

template <int EPI>
__device__ __forceinline__ void gemm_core(
    const unsigned short* __restrict__ A, int lda, int K,
    const int* __restrict__ order, bool gather, int rowbase,
    const unsigned short* __restrict__ Be,
    const float* __restrict__ bias1e, const float* __restrict__ bias3e,
    int ncolbase, void* __restrict__ outp, int ldo,
    const int* __restrict__ tokmap, const float* __restrict__ wslot,
    unsigned short* lds) {
  int tid = threadIdx.x;
  int lane = tid & 63, wid = tid >> 6;
  int wr = wid >> 1, wc = wid & 1;            // 4 x 2 wave grid: 64 rows x 64 cols each

  size_t aoff[4], boff[2];
#pragma unroll
  for (int l = 0; l < 4; ++l) {
    int g = l * 512 + tid;
    int r = g >> 3;
    int sub = (g & 7) ^ (r & 7);
    int gr = gather ? order[rowbase + r] : (rowbase + r);
    aoff[l] = (size_t)gr * lda + (size_t)(sub * 8);
  }
#pragma unroll
  for (int l = 0; l < 2; ++l) {
    int g = l * 512 + tid;
    int r = g >> 3;
    int sub = (g & 7) ^ (r & 7);
    boff[l] = (size_t)(ncolbase + r) * K + (size_t)(sub * 8);
  }

  f32x4 acc[4][4];
#pragma unroll
  for (int m = 0; m < 4; ++m)
#pragma unroll
    for (int n = 0; n < 4; ++n) acc[m][n] = f32x4{0.f, 0.f, 0.f, 0.f};

  const int NT = K >> 6;

  // prologue: stage tiles 0 and 1
#pragma unroll
  for (int l = 0; l < 4; ++l)
    gload16(A + aoff[l], &lds[(size_t)(l * 512 + tid) * 8]);
#pragma unroll
  for (int l = 0; l < 2; ++l)
    gload16(Be + boff[l], &lds[A_ELE + (size_t)(l * 512 + tid) * 8]);
#pragma unroll
  for (int l = 0; l < 4; ++l)
    gload16(A + aoff[l] + 64, &lds[BUF_ELE + (size_t)(l * 512 + tid) * 8]);
#pragma unroll
  for (int l = 0; l < 2; ++l)
    gload16(Be + boff[l] + 64, &lds[BUF_ELE + A_ELE + (size_t)(l * 512 + tid) * 8]);

  unsigned int off_r = 0, off_m = BUF_ELE, off_w = 2 * BUF_ELE;

  for (int t = 0; t < NT; ++t) {
    if (t + 1 < NT) {
      asm volatile("s_waitcnt vmcnt(6)" ::: "memory");
    } else {
      asm volatile("s_waitcnt vmcnt(0)" ::: "memory");
    }
    asm volatile("s_waitcnt lgkmcnt(0)" ::: "memory");
    barrier_nodrain();   // tile t visible; write-target buffer free of readers

    const unsigned short* Ab = &lds[off_r];
    const unsigned short* Bb = &lds[off_r + A_ELE];
    const bool st = (t + 2 < NT);
    const int kb = (t + 2) << 6;

    // ---- half kk=0: ds_reads, stage A, MFMA ----
    {
      bf16x8 a[4], b[4];
#pragma unroll
      for (int m = 0; m < 4; ++m) {
        int ra = wr * 64 + m * 16 + (lane & 15);
        int sa = ((lane >> 4)) ^ (ra & 7);
        a[m] = *(const bf16x8*)&Ab[ra * 64 + sa * 8];
      }
#pragma unroll
      for (int n = 0; n < 4; ++n) {
        int rb = wc * 64 + n * 16 + (lane & 15);
        int sb = ((lane >> 4)) ^ (rb & 7);
        b[n] = *(const bf16x8*)&Bb[rb * 64 + sb * 8];
      }
      if (st) {
#pragma unroll
        for (int l = 0; l < 4; ++l)
          gload16(A + aoff[l] + kb, &lds[off_w + (size_t)(l * 512 + tid) * 8]);
      }
      __builtin_amdgcn_s_setprio(1);
#pragma unroll
      for (int m = 0; m < 4; ++m)
#pragma unroll
        for (int n = 0; n < 4; ++n)
          acc[m][n] = __builtin_amdgcn_mfma_f32_16x16x32_bf16(a[m], b[n], acc[m][n], 0, 0, 0);
      __builtin_amdgcn_s_setprio(0);
    }
    // ---- half kk=1: ds_reads, stage B, MFMA ----
    {
      bf16x8 a[4], b[4];
#pragma unroll
      for (int m = 0; m < 4; ++m) {
        int ra = wr * 64 + m * 16 + (lane & 15);
        int sa = (4 + (lane >> 4)) ^ (ra & 7);
        a[m] = *(const bf16x8*)&Ab[ra * 64 + sa * 8];
      }
#pragma unroll
      for (int n = 0; n < 4; ++n) {
        int rb = wc * 64 + n * 16 + (lane & 15);
        int sb = (4 + (lane >> 4)) ^ (rb & 7);
        b[n] = *(const bf16x8*)&Bb[rb * 64 + sb * 8];
      }
      if (st) {
#pragma unroll
        for (int l = 0; l < 2; ++l)
          gload16(Be + boff[l] + kb, &lds[off_w + A_ELE + (size_t)(l * 512 + tid) * 8]);
      }
      __builtin_amdgcn_s_setprio(1);
#pragma unroll
      for (int m = 0; m < 4; ++m)
#pragma unroll
        for (int n = 0; n < 4; ++n)
          acc[m][n] = __builtin_amdgcn_mfma_f32_16x16x32_bf16(a[m], b[n], acc[m][n], 0, 0, 0);
      __builtin_amdgcn_s_setprio(0);
    }

    unsigned int tmp = off_r; off_r = off_m; off_m = off_w; off_w = tmp;
  }

  if (EPI == 0) {
#pragma unroll
    for (int m = 0; m < 4; ++m)
#pragma unroll
      for (int np = 0; np < 2; ++np) {
        int realcol = (ncolbase >> 1) + wc * 32 + np * 16 + (lane & 15);
        float bb1 = bias1e[realcol];
        float bb3 = bias3e[realcol];
#pragma unroll
        for (int j = 0; j < 4; ++j) {
          int row  = rowbase + wr * 64 + m * 16 + (lane >> 4) * 4 + j;
          float a1 = acc[m][2 * np][j] + bb1;
          float a3 = acc[m][2 * np + 1][j] + bb3;
          float hv = (a1 / (1.f + __expf(-a1))) * a3;   // silu(a1)*a3
          ((unsigned short*)outp)[(size_t)row * ldo + realcol] = f2b(hv);
        }
      }
  } else if (EPI == 2) {
#pragma unroll
    for (int m = 0; m < 4; ++m)
#pragma unroll
      for (int n = 0; n < 4; ++n) {
        int col  = ncolbase + wc * 64 + n * 16 + (lane & 15);
        float bb = bias1e[col];
#pragma unroll
        for (int j = 0; j < 4; ++j) {
          int row = rowbase + wr * 64 + m * 16 + (lane >> 4) * 4 + j;
          ((float*)outp)[(size_t)row * ldo + col] = acc[m][n][j] + bb;
        }
      }
  } else {   // EPI == 3: atomic combine into out (pads have wslot==0 -> add 0)
#pragma unroll
    for (int m = 0; m < 4; ++m) {
#pragma unroll
      for (int j = 0; j < 4; ++j) {
        int row = rowbase + wr * 64 + m * 16 + (lane >> 4) * 4 + j;
        int tok = tokmap[row];
        float wg = wslot[row];
#pragma unroll
        for (int n = 0; n < 4; ++n) {
          int col  = ncolbase + wc * 64 + n * 16 + (lane & 15);
          float v  = wg * (acc[m][n][j] + bias1e[col]);
          atomicAdd(&((float*)outp)[(size_t)tok * ldo + col], v);
        }
      }
    }
  }
}

// ---------- merged gemm1 (routed + shared), one launch, XCD-swizzled 1D grid -------
__global__ __launch_bounds__(512) void gemm1m_kernel(
    const unsigned short* __restrict__ xb,
    const int* __restrict__ order, const int* __restrict__ poff,
    const unsigned short* __restrict__ w13r,
    const float* __restrict__ b1, const float* __restrict__ b3,
    const unsigned short* __restrict__ w13s,
    const float* __restrict__ bs1, const float* __restrict__ bs3,
    unsigned short* __restrict__ h, unsigned short* __restrict__ hs) {
  __shared__ unsigned short lds[3 * BUF_ELE];   // 144 KiB

  int raw = blockIdx.x;
  int id  = (raw & 7) * (G1 / 8) + (raw >> 3);   // bijective XCD swizzle (G1 % 8 == 0)

  if (id < G1R) {
    int by = id / NS1_R, bx = id - by * NS1_R;
    int rowbase = by * 256;
    if (rowbase >= poff[NEXP]) return;
    int expert = 0;
    while (expert < NEXP - 1 && rowbase >= poff[expert + 1]) ++expert;
    gemm_core<0>(xb, DIMK, DIMK, order, true, rowbase,
                 w13r + (size_t)expert * 2 * INTERK * DIMK,
                 b1 + expert * INTERK, b3 + expert * INTERK,
                 bx * 128, (void*)h, INTERK, nullptr, nullptr, lds);
  } else {
    int id2 = id - G1R;
    int by = id2 / NS1_S, bx = id2 - by * NS1_S;
    gemm_core<0>(xb, DIMK, DIMK, (const int*)nullptr, false, by * 256,
                 w13s, bs1, bs3,
                 bx * 128, (void*)hs, SINT, nullptr, nullptr, lds);
  }
}

// ---------- shared gemm2: plain f32 stores of z into out (runs BEFORE routed) -----
__global__ __launch_bounds__(512) void gemm2s_kernel(
    const unsigned short* __restrict__ hs,
    const unsigned short* __restrict__ ws2b, const float* __restrict__ bs2,
    float* __restrict__ out) {
  __shared__ unsigned short lds[3 * BUF_ELE];   // 144 KiB
  int raw = blockIdx.x;
  int id  = (raw & 7) * (G2S / 8) + (raw >> 3);   // bijective (G2S % 8 == 0)
  int by = id / NS2, bx = id - by * NS2;
  gemm_core<2>(hs, SINT, SINT, (const int*)nullptr, false, by * 256,
               ws2b, bs2, (const float*)nullptr,
               bx * 128, (void*)out, DIMK, nullptr, nullptr, lds);
}

// ---------- routed gemm2: fused combine via atomicAdd into out -------------------
__global__ __launch_bounds__(512) void gemm2r_kernel(
    const unsigned short* __restrict__ h, const int* __restrict__ poff,
    const unsigned short* __restrict__ w2b, const float* __restrict__ b2,
    const int* __restrict__ order, const float* __restrict__ wslot,
    float* __restrict__ out) {
  __shared__ unsigned short lds[3 * BUF_ELE];   // 144 KiB
  int raw = blockIdx.x;
  int id  = (raw & 7) * (G2R / 8) + (raw >> 3);   // bijective (G2R % 8 == 0)
  int by = id / NS2, bx = id - by * NS2;
  int rowbase = by * 256;
  if (rowbase >= poff[NEXP]) return;
  int expert = 0;
  while (expert < NEXP - 1 && rowbase >= poff[expert + 1]) ++expert;
  gemm_core<3>(h, INTERK, INTERK, (const int*)nullptr, false, rowbase,
               w2b + (size_t)expert * DIMK * INTERK,
               b2 + expert * DIMK, (const float*)nullptr,
               bx * 128, (void*)out, DIMK, order, wslot, lds);
}

// ---------------- launch ----------------
extern "C" void kernel_launch(void* const* d_in, const int* in_sizes, int n_in,
                              void* d_out, int out_size, void* d_ws, size_t ws_size,
                              hipStream_t stream) {
  const float* x   = (const float*)d_in[0];
  const float* gw  = (const float*)d_in[1];
  const float* gb  = (const float*)d_in[2];
  const float* w1  = (const float*)d_in[3];
  const float* b1  = (const float*)d_in[4];
  const float* w3  = (const float*)d_in[5];
  const float* b3  = (const float*)d_in[6];
  const float* w2  = (const float*)d_in[7];
  const float* b2  = (const float*)d_in[8];
  const float* ws1 = (const float*)d_in[9];
  const float* bs1 = (const float*)d_in[10];
  const float* ws3 = (const float*)d_in[11];
  const float* bs3 = (const float*)d_in[12];
  const float* ws2 = (const float*)d_in[13];
  const float* bs2 = (const float*)d_in[14];
  float* out = (float*)d_out;
  (void)in_sizes; (void)n_in; (void)out_size; (void)ws_size;

  char* p = (char*)d_ws;
  auto alloc = [&](size_t bytes) -> void* {
    void* r = (void*)p;
    p += (bytes + 255) & ~(size_t)255;
    return r;
  };
  unsigned short* xb    = (unsigned short*)alloc((size_t)T_TOK * DIMK * 2);
  unsigned short* w13r  = (unsigned short*)alloc((size_t)NEXP * 2 * INTERK * DIMK * 2);
  unsigned short* w2b   = (unsigned short*)alloc((size_t)NEXP * DIMK * INTERK * 2);
  unsigned short* w13s  = (unsigned short*)alloc((size_t)2 * SINT * DIMK * 2);
  unsigned short* ws2b  = (unsigned short*)alloc((size_t)DIMK * SINT * 2);
  unsigned short* h     = (unsigned short*)alloc((size_t)CAP * INTERK * 2);
  unsigned short* hs    = (unsigned short*)alloc((size_t)T_TOK * SINT * 2);
  int*   top_i  = (int*)alloc((size_t)T_TOK * 2 * 4);
  float* top_w  = (float*)alloc((size_t)T_TOK * 2 * 4);
  int*   order  = (int*)alloc((size_t)CAP * 4);
  float* wslot  = (float*)alloc((size_t)CAP * 4);
  int*   poff   = (int*)alloc(64);

  // merged gate(+x cvt) + all weight converts, then routing build
  cvtgate_kernel<<<GATE_BLOCKS + WCVT_BLOCKS, 256, 0, stream>>>(
      x, gw, gb, top_i, top_w, xb,
      (const float4*)w1, (const float4*)w3, (const float4*)ws1, (const float4*)ws3,
      (const float4*)w2, (const float4*)ws2, w13r, w13s, w2b, ws2b);
  route_build_kernel<<<1, 512, 0, stream>>>(top_i, top_w, order, wslot, poff);

  // merged gemm1 (routed + shared)
  gemm1m_kernel<<<G1, 512, 0, stream>>>(xb, order, poff, w13r, b1, b3,
                                        w13s, bs1, bs3, h, hs);

  // shared gemm2 writes z into out; routed gemm2 atomically adds w * (h@w2^T + b2)
  gemm2s_kernel<<<G2S, 512, 0, stream>>>(hs, ws2b, bs2, out);
  gemm2r_kernel<<<G2R, 512, 0, stream>>>(h, poff, w2b, b2, order, wslot, out);
}

// Round 16
// 366.963 us; speedup vs baseline: 1.2226x; 1.2226x over previous
//
#include <hip/hip_runtime.h>
#include <stdint.h>
#include <stddef.h>

// ---------------- problem constants ----------------
#define T_TOK  8192        // B*S tokens
#define DIMK   1024        // model dim
#define INTERK 1024        // routed expert inter dim
#define NEXP   8
#define SINT   2048        // shared inter dim
#define CAP    18432       // 2*T + 8*256 padding capacity (slot rows, 256-aligned)
#define RT256  72          // CAP/256 row tiles (worst case)

#define NS1_R  16          // gemm1 routed N-slices (2*INTERK/128)
#define NS1_S  32          // gemm1 shared N-slices (2*SINT/128)
#define RT_S   32          // shared row tiles (T_TOK/256)
#define G1R    (NS1_R * RT256)          // 1152
#define G1     (G1R + NS1_S * RT_S)     // 2176
#define NS2    8           // gemm2 N-slices (DIMK/128)
#define G2R    (NS2 * RT256)            // 576
#define G2     (G2R + NS2 * RT_S)       // 832

typedef float  f32x4  __attribute__((ext_vector_type(4)));
typedef short  bf16x8 __attribute__((ext_vector_type(8)));

typedef __attribute__((address_space(1))) const unsigned int gas_u32;
typedef __attribute__((address_space(3))) unsigned int las_u32;

__device__ __forceinline__ void gload16(const void* g, void* l) {
  __builtin_amdgcn_global_load_lds((gas_u32*)g, (las_u32*)l, 16, 0, 0);
}

__device__ __forceinline__ unsigned short f2b(float f) {   // f32 -> bf16 RNE
  unsigned int u = __float_as_uint(f);
  u = (u + 0x7FFFu + ((u >> 16) & 1u)) >> 16;
  return (unsigned short)u;
}
__device__ __forceinline__ float b2f(unsigned short h) {
  return __uint_as_float(((unsigned int)h) << 16);
}

// raw barrier with compile-time memory fences (no vmcnt/lgkmcnt drain)
__device__ __forceinline__ void barrier_nodrain() {
  asm volatile("" ::: "memory");
  __builtin_amdgcn_s_barrier();
  asm volatile("" ::: "memory");
}

// ------- merged: gate (+x->bf16 convert) AND all weight converts, one launch -------
#define N1C 2097152   // NEXP*INTERK*(DIMK/4)
#define N2C 524288    // SINT*(DIMK/4)
#define N3C 2097152   // NEXP*DIMK*(INTERK/4)
#define N4C 524288    // DIMK*(SINT/4)
#define GATE_BLOCKS (T_TOK / 4)
#define WCVT_BLOCKS ((2*N1C + 2*N2C + N3C + N4C) / 256)   // 30720
__global__ __launch_bounds__(256) void cvtgate_kernel(
    const float* __restrict__ x, const float* __restrict__ gw, const float* __restrict__ gb,
    int* __restrict__ top_i, float* __restrict__ top_w, unsigned short* __restrict__ xb,
    const float4* __restrict__ w1, const float4* __restrict__ w3,
    const float4* __restrict__ ws1, const float4* __restrict__ ws3,
    const float4* __restrict__ w2, const float4* __restrict__ ws2,
    unsigned short* __restrict__ w13r, unsigned short* __restrict__ w13s,
    unsigned short* __restrict__ w2b, unsigned short* __restrict__ ws2b) {
  int bid = blockIdx.x;
  if (bid < GATE_BLOCKS) {
    int t    = bid * 4 + (threadIdx.x >> 6);
    int lane = threadIdx.x & 63;
    const float* xr = x + (size_t)t * DIMK;
    unsigned short* xo = xb + (size_t)t * DIMK;
    float acc[NEXP];
#pragma unroll
    for (int e = 0; e < NEXP; ++e) acc[e] = 0.f;
    for (int i = lane; i < DIMK; i += 64) {
      float xv = xr[i];
      xo[i] = f2b(xv);
#pragma unroll
      for (int e = 0; e < NEXP; ++e) acc[e] += xv * gw[e * DIMK + i];
    }
#pragma unroll
    for (int e = 0; e < NEXP; ++e) {
      float v = acc[e];
#pragma unroll
      for (int off = 32; off > 0; off >>= 1) v += __shfl_down(v, off, 64);
      acc[e] = v;
    }
    if (lane == 0) {
      float lg[NEXP];
#pragma unroll
      for (int e = 0; e < NEXP; ++e) lg[e] = acc[e] + gb[e];
      int i0 = 0;
#pragma unroll
      for (int e = 1; e < NEXP; ++e) if (lg[e] > lg[i0]) i0 = e;   // first index wins ties
      int i1 = (i0 == 0) ? 1 : 0;
#pragma unroll
      for (int e = 0; e < NEXP; ++e) if (e != i0 && lg[e] > lg[i1]) i1 = e;
      float mx = lg[i0], s = 0.f;
#pragma unroll
      for (int e = 0; e < NEXP; ++e) s += expf(lg[e] - mx);
      top_i[t * 2]     = i0;
      top_i[t * 2 + 1] = i1;
      top_w[t * 2]     = expf(lg[i0] - mx) / s;
      top_w[t * 2 + 1] = expf(lg[i1] - mx) / s;
    }
    return;
  }
  long long i = (long long)(bid - GATE_BLOCKS) * 256 + threadIdx.x;
  float4 v;
  unsigned short* dst;
  size_t didx;
  if (i < 2 * (long long)N1C) {
    int is3 = i >= N1C;
    int j = (int)(i - (long long)is3 * N1C);
    int r = j >> 8, kc = j & 255;
    int e = r >> 10, rr = r & 1023, g = rr >> 4;
    size_t dst_r = (size_t)e * (2 * INTERK) + g * 32 + (is3 ? 16 : 0) + (rr & 15);
    v = (is3 ? w3 : w1)[j];
    dst = w13r; didx = dst_r * 256 + kc;
  } else if ((i -= 2 * (long long)N1C) < 2 * (long long)N2C) {
    int is3 = i >= N2C;
    int j = (int)(i - (long long)is3 * N2C);
    int r = j >> 8, kc = j & 255;
    int g = r >> 4;
    size_t dst_r = (size_t)g * 32 + (is3 ? 16 : 0) + (r & 15);
    v = (is3 ? ws3 : ws1)[j];
    dst = w13s; didx = dst_r * 256 + kc;
  } else if ((i -= 2 * (long long)N2C) < (long long)N3C) {
    int j = (int)i;
    v = w2[j];
    dst = w2b; didx = (size_t)j;
  } else {
    int j = (int)(i - N3C);
    v = ws2[j];
    dst = ws2b; didx = (size_t)j;
  }
  ushort4 o;
  o.x = f2b(v.x); o.y = f2b(v.y); o.z = f2b(v.z); o.w = f2b(v.w);
  *reinterpret_cast<ushort4*>(&dst[didx * 4]) = o;
}

// ---------------- route_build: count + scan + slot-assign, deterministic ----------
__global__ __launch_bounds__(512) void route_build_kernel(
    const int* __restrict__ top_i, int* __restrict__ order, int* __restrict__ pos,
    int* __restrict__ poff_g) {
  __shared__ int cnt[NEXP][512];
  __shared__ int base[NEXP][512];
  __shared__ int totals[NEXP];
  __shared__ int poff_s[NEXP + 1];
  int tid = threadIdx.x;
  int lane = tid & 63, w = tid >> 6;
  const int t0 = tid * 16;

  int c[NEXP];
#pragma unroll
  for (int e = 0; e < NEXP; ++e) c[e] = 0;
  for (int j = 0; j < 16; ++j) {
    int e0 = top_i[(t0 + j) * 2];
    int e1 = top_i[(t0 + j) * 2 + 1];
#pragma unroll
    for (int e = 0; e < NEXP; ++e) c[e] += (e0 == e) + (e1 == e);
  }
#pragma unroll
  for (int e = 0; e < NEXP; ++e) cnt[e][tid] = c[e];
  __syncthreads();

  {
    int running = 0;
    for (int ch = 0; ch < 8; ++ch) {
      int v = cnt[w][ch * 64 + lane];
      int incl = v;
#pragma unroll
      for (int off = 1; off < 64; off <<= 1) {
        int u = __shfl_up(incl, off, 64);
        if (lane >= off) incl += u;
      }
      base[w][ch * 64 + lane] = running + incl - v;
      running += __shfl(incl, 63, 64);
    }
    if (lane == 0) totals[w] = running;
  }
  __syncthreads();

  if (tid == 0) {
    int off = 0;
#pragma unroll
    for (int e = 0; e < NEXP; ++e) {
      poff_s[e] = off;
      off += (totals[e] + 255) & ~255;
    }
    poff_s[NEXP] = off;
#pragma unroll
    for (int e = 0; e <= NEXP; ++e) poff_g[e] = poff_s[e];
  }
  __syncthreads();

  int cur[NEXP];
#pragma unroll
  for (int e = 0; e < NEXP; ++e) cur[e] = poff_s[e] + base[e][tid];
  for (int j = 0; j < 16; ++j) {
    int t = t0 + j;
#pragma unroll
    for (int k = 0; k < 2; ++k) {
      int ei = top_i[t * 2 + k];
      int p = 0;
#pragma unroll
      for (int e = 0; e < NEXP; ++e)
        if (ei == e) { p = cur[e]; cur[e] = p + 1; }
      order[p]       = t;
      pos[t * 2 + k] = p;
    }
  }

#pragma unroll
  for (int e = 0; e < NEXP; ++e) {
    int s = poff_s[e] + totals[e], en = poff_s[e + 1];
    for (int i = s + tid; i < en; i += 512) order[i] = 0;
  }
}

// ====== core round-8 GEMM body: BM=256, BN=128, BK=64, 512 thr (8 waves 4x2) ======
// Depth-2 prefetch, 3 LDS buffers (144 KB), counted vmcnt(6), one barrier per tile,
// loose compiler-scheduled body, setprio around MFMA clusters, XOR-swizzled LDS.
#define A_ELE   16384   // 256*64 elements per A buffer
#define B_ELE   8192    // 128*64 elements per B buffer
#define BUF_ELE (A_ELE + B_ELE)

template <bool SWIGLU>
__device__ __forceinline__ void gemm_core(
    const unsigned short* __restrict__ A, int lda, int K,
    const int* __restrict__ order, bool gather, int rowbase,
    const unsigned short* __restrict__ Be,
    const float* __restrict__ bias1e, const float* __restrict__ bias3e,
    int ncolbase, void* __restrict__ outp, int ldo, bool outf32,
    unsigned short* lds) {
  int tid = threadIdx.x;
  int lane = tid & 63, wid = tid >> 6;
  int wr = wid >> 1, wc = wid & 1;            // 4 x 2 wave grid: 64 rows x 64 cols each

  size_t aoff[4], boff[2];
#pragma unroll
  for (int l = 0; l < 4; ++l) {
    int g = l * 512 + tid;
    int r = g >> 3;
    int sub = (g & 7) ^ (r & 7);
    int gr = gather ? order[rowbase + r] : (rowbase + r);
    aoff[l] = (size_t)gr * lda + (size_t)(sub * 8);
  }
#pragma unroll
  for (int l = 0; l < 2; ++l) {
    int g = l * 512 + tid;
    int r = g >> 3;
    int sub = (g & 7) ^ (r & 7);
    boff[l] = (size_t)(ncolbase + r) * K + (size_t)(sub * 8);
  }

  f32x4 acc[4][4];
#pragma unroll
  for (int m = 0; m < 4; ++m)
#pragma unroll
    for (int n = 0; n < 4; ++n) acc[m][n] = f32x4{0.f, 0.f, 0.f, 0.f};

  const int NT = K >> 6;

  // prologue: stage tiles 0 and 1
#pragma unroll
  for (int l = 0; l < 4; ++l)
    gload16(A + aoff[l], &lds[(size_t)(l * 512 + tid) * 8]);
#pragma unroll
  for (int l = 0; l < 2; ++l)
    gload16(Be + boff[l], &lds[A_ELE + (size_t)(l * 512 + tid) * 8]);
#pragma unroll
  for (int l = 0; l < 4; ++l)
    gload16(A + aoff[l] + 64, &lds[BUF_ELE + (size_t)(l * 512 + tid) * 8]);
#pragma unroll
  for (int l = 0; l < 2; ++l)
    gload16(Be + boff[l] + 64, &lds[BUF_ELE + A_ELE + (size_t)(l * 512 + tid) * 8]);

  unsigned int off_r = 0, off_m = BUF_ELE, off_w = 2 * BUF_ELE;

  for (int t = 0; t < NT; ++t) {
    if (t + 1 < NT) {
      asm volatile("s_waitcnt vmcnt(6)" ::: "memory");
    } else {
      asm volatile("s_waitcnt vmcnt(0)" ::: "memory");
    }
    asm volatile("s_waitcnt lgkmcnt(0)" ::: "memory");
    barrier_nodrain();   // tile t visible; write-target buffer free of readers

    const unsigned short* Ab = &lds[off_r];
    const unsigned short* Bb = &lds[off_r + A_ELE];
    const bool st = (t + 2 < NT);
    const int kb = (t + 2) << 6;

    // ---- half kk=0: ds_reads, stage A, MFMA ----
    {
      bf16x8 a[4], b[4];
#pragma unroll
      for (int m = 0; m < 4; ++m) {
        int ra = wr * 64 + m * 16 + (lane & 15);
        int sa = ((lane >> 4)) ^ (ra & 7);
        a[m] = *(const bf16x8*)&Ab[ra * 64 + sa * 8];
      }
#pragma unroll
      for (int n = 0; n < 4; ++n) {
        int rb = wc * 64 + n * 16 + (lane & 15);
        int sb = ((lane >> 4)) ^ (rb & 7);
        b[n] = *(const bf16x8*)&Bb[rb * 64 + sb * 8];
      }
      if (st) {
#pragma unroll
        for (int l = 0; l < 4; ++l)
          gload16(A + aoff[l] + kb, &lds[off_w + (size_t)(l * 512 + tid) * 8]);
      }
      __builtin_amdgcn_s_setprio(1);
#pragma unroll
      for (int m = 0; m < 4; ++m)
#pragma unroll
        for (int n = 0; n < 4; ++n)
          acc[m][n] = __builtin_amdgcn_mfma_f32_16x16x32_bf16(a[m], b[n], acc[m][n], 0, 0, 0);
      __builtin_amdgcn_s_setprio(0);
    }
    // ---- half kk=1: ds_reads, stage B, MFMA ----
    {
      bf16x8 a[4], b[4];
#pragma unroll
      for (int m = 0; m < 4; ++m) {
        int ra = wr * 64 + m * 16 + (lane & 15);
        int sa = (4 + (lane >> 4)) ^ (ra & 7);
        a[m] = *(const bf16x8*)&Ab[ra * 64 + sa * 8];
      }
#pragma unroll
      for (int n = 0; n < 4; ++n) {
        int rb = wc * 64 + n * 16 + (lane & 15);
        int sb = (4 + (lane >> 4)) ^ (rb & 7);
        b[n] = *(const bf16x8*)&Bb[rb * 64 + sb * 8];
      }
      if (st) {
#pragma unroll
        for (int l = 0; l < 2; ++l)
          gload16(Be + boff[l] + kb, &lds[off_w + A_ELE + (size_t)(l * 512 + tid) * 8]);
      }
      __builtin_amdgcn_s_setprio(1);
#pragma unroll
      for (int m = 0; m < 4; ++m)
#pragma unroll
        for (int n = 0; n < 4; ++n)
          acc[m][n] = __builtin_amdgcn_mfma_f32_16x16x32_bf16(a[m], b[n], acc[m][n], 0, 0, 0);
      __builtin_amdgcn_s_setprio(0);
    }

    unsigned int tmp = off_r; off_r = off_m; off_m = off_w; off_w = tmp;
  }

  if (SWIGLU) {
#pragma unroll
    for (int m = 0; m < 4; ++m)
#pragma unroll
      for (int np = 0; np < 2; ++np) {
        int realcol = (ncolbase >> 1) + wc * 32 + np * 16 + (lane & 15);
        float bb1 = bias1e[realcol];
        float bb3 = bias3e[realcol];
#pragma unroll
        for (int j = 0; j < 4; ++j) {
          int row  = rowbase + wr * 64 + m * 16 + (lane >> 4) * 4 + j;
          float a1 = acc[m][2 * np][j] + bb1;
          float a3 = acc[m][2 * np + 1][j] + bb3;
          float hv = (a1 / (1.f + __expf(-a1))) * a3;   // silu(a1)*a3
          ((unsigned short*)outp)[(size_t)row * ldo + realcol] = f2b(hv);
        }
      }
  } else {
#pragma unroll
    for (int m = 0; m < 4; ++m)
#pragma unroll
      for (int n = 0; n < 4; ++n) {
        int col  = ncolbase + wc * 64 + n * 16 + (lane & 15);
        float bb = bias1e[col];
#pragma unroll
        for (int j = 0; j < 4; ++j) {
          int row = rowbase + wr * 64 + m * 16 + (lane >> 4) * 4 + j;
          float v = acc[m][n][j] + bb;
          if (outf32)
            ((float*)outp)[(size_t)row * ldo + col] = v;
          else
            ((unsigned short*)outp)[(size_t)row * ldo + col] = f2b(v);
        }
      }
  }
}

// ---------- merged gemm1 (routed + shared), one launch, XCD-swizzled 1D grid -------
__global__ __launch_bounds__(512) void gemm1m_kernel(
    const unsigned short* __restrict__ xb,
    const int* __restrict__ order, const int* __restrict__ poff,
    const unsigned short* __restrict__ w13r,
    const float* __restrict__ b1, const float* __restrict__ b3,
    const unsigned short* __restrict__ w13s,
    const float* __restrict__ bs1, const float* __restrict__ bs3,
    unsigned short* __restrict__ h, unsigned short* __restrict__ hs) {
  __shared__ unsigned short lds[3 * BUF_ELE];   // 144 KiB

  int raw = blockIdx.x;
  int id  = (raw & 7) * (G1 / 8) + (raw >> 3);   // bijective XCD swizzle (G1 % 8 == 0)

  if (id < G1R) {
    int by = id / NS1_R, bx = id - by * NS1_R;
    int rowbase = by * 256;
    if (rowbase >= poff[NEXP]) return;
    int expert = 0;
    while (expert < NEXP - 1 && rowbase >= poff[expert + 1]) ++expert;
    gemm_core<true>(xb, DIMK, DIMK, order, true, rowbase,
                    w13r + (size_t)expert * 2 * INTERK * DIMK,
                    b1 + expert * INTERK, b3 + expert * INTERK,
                    bx * 128, (void*)h, INTERK, false, lds);
  } else {
    int id2 = id - G1R;
    int by = id2 / NS1_S, bx = id2 - by * NS1_S;
    gemm_core<true>(xb, DIMK, DIMK, (const int*)nullptr, false, by * 256,
                    w13s, bs1, bs3,
                    bx * 128, (void*)hs, SINT, false, lds);
  }
}

// ---------- merged gemm2 (routed + shared), one launch, XCD-swizzled 1D grid -------
__global__ __launch_bounds__(512) void gemm2m_kernel(
    const unsigned short* __restrict__ h, const unsigned short* __restrict__ hs,
    const int* __restrict__ poff,
    const unsigned short* __restrict__ w2b, const float* __restrict__ b2,
    const unsigned short* __restrict__ ws2b, const float* __restrict__ bs2,
    unsigned short* __restrict__ yb, float* __restrict__ out) {
  __shared__ unsigned short lds[3 * BUF_ELE];   // 144 KiB

  int raw = blockIdx.x;
  int id  = (raw & 7) * (G2 / 8) + (raw >> 3);   // bijective XCD swizzle (G2 % 8 == 0)

  if (id < G2R) {
    int by = id / NS2, bx = id - by * NS2;
    int rowbase = by * 256;
    if (rowbase >= poff[NEXP]) return;
    int expert = 0;
    while (expert < NEXP - 1 && rowbase >= poff[expert + 1]) ++expert;
    gemm_core<false>(h, INTERK, INTERK, (const int*)nullptr, false, rowbase,
                     w2b + (size_t)expert * DIMK * INTERK,
                     b2 + expert * DIMK, (const float*)nullptr,
                     bx * 128, (void*)yb, DIMK, false, lds);
  } else {
    int id2 = id - G2R;
    int by = id2 / NS2, bx = id2 - by * NS2;
    gemm_core<false>(hs, SINT, SINT, (const int*)nullptr, false, by * 256,
                     ws2b, bs2, (const float*)nullptr,
                     bx * 128, (void*)out, DIMK, true, lds);
  }
}

// ------------- combine (vectorized): out4 += w0*y4[p0] + w1*y4[p1] ----------------
// one block per token (256 threads x float4 = 1024 cols)
__global__ __launch_bounds__(256) void combine4_kernel(
    float* __restrict__ out, const unsigned short* __restrict__ y,
    const int* __restrict__ pos, const float* __restrict__ tw) {
  int t  = blockIdx.x;
  int d4 = threadIdx.x;
  int p0 = pos[t * 2], p1 = pos[t * 2 + 1];
  float w0 = tw[t * 2], w1 = tw[t * 2 + 1];
  ushort4 y0 = ((const ushort4*)(y + (size_t)p0 * DIMK))[d4];
  ushort4 y1 = ((const ushort4*)(y + (size_t)p1 * DIMK))[d4];
  float4* o4 = (float4*)(out + (size_t)t * DIMK);
  float4 o = o4[d4];
  o.x += w0 * b2f(y0.x) + w1 * b2f(y1.x);
  o.y += w0 * b2f(y0.y) + w1 * b2f(y1.y);
  o.z += w0 * b2f(y0.z) + w1 * b2f(y1.z);
  o.w += w0 * b2f(y0.w) + w1 * b2f(y1.w);
  o4[d4] = o;
}

// ---------------- launch ----------------
extern "C" void kernel_launch(void* const* d_in, const int* in_sizes, int n_in,
                              void* d_out, int out_size, void* d_ws, size_t ws_size,
                              hipStream_t stream) {
  const float* x   = (const float*)d_in[0];
  const float* gw  = (const float*)d_in[1];
  const float* gb  = (const float*)d_in[2];
  const float* w1  = (const float*)d_in[3];
  const float* b1  = (const float*)d_in[4];
  const float* w3  = (const float*)d_in[5];
  const float* b3  = (const float*)d_in[6];
  const float* w2  = (const float*)d_in[7];
  const float* b2  = (const float*)d_in[8];
  const float* ws1 = (const float*)d_in[9];
  const float* bs1 = (const float*)d_in[10];
  const float* ws3 = (const float*)d_in[11];
  const float* bs3 = (const float*)d_in[12];
  const float* ws2 = (const float*)d_in[13];
  const float* bs2 = (const float*)d_in[14];
  float* out = (float*)d_out;
  (void)in_sizes; (void)n_in; (void)out_size; (void)ws_size;

  char* p = (char*)d_ws;
  auto alloc = [&](size_t bytes) -> void* {
    void* r = (void*)p;
    p += (bytes + 255) & ~(size_t)255;
    return r;
  };
  unsigned short* xb    = (unsigned short*)alloc((size_t)T_TOK * DIMK * 2);
  unsigned short* w13r  = (unsigned short*)alloc((size_t)NEXP * 2 * INTERK * DIMK * 2);
  unsigned short* w2b   = (unsigned short*)alloc((size_t)NEXP * DIMK * INTERK * 2);
  unsigned short* w13s  = (unsigned short*)alloc((size_t)2 * SINT * DIMK * 2);
  unsigned short* ws2b  = (unsigned short*)alloc((size_t)DIMK * SINT * 2);
  unsigned short* h     = (unsigned short*)alloc((size_t)CAP * INTERK * 2);
  unsigned short* yb    = (unsigned short*)alloc((size_t)CAP * DIMK * 2);
  unsigned short* hs    = (unsigned short*)alloc((size_t)T_TOK * SINT * 2);
  int*   top_i  = (int*)alloc((size_t)T_TOK * 2 * 4);
  float* top_w  = (float*)alloc((size_t)T_TOK * 2 * 4);
  int*   pos    = (int*)alloc((size_t)T_TOK * 2 * 4);
  int*   order  = (int*)alloc((size_t)CAP * 4);
  int*   poff   = (int*)alloc(64);

  // merged gate(+x cvt) + all weight converts, then routing build
  cvtgate_kernel<<<GATE_BLOCKS + WCVT_BLOCKS, 256, 0, stream>>>(
      x, gw, gb, top_i, top_w, xb,
      (const float4*)w1, (const float4*)w3, (const float4*)ws1, (const float4*)ws3,
      (const float4*)w2, (const float4*)ws2, w13r, w13s, w2b, ws2b);
  route_build_kernel<<<1, 512, 0, stream>>>(top_i, order, pos, poff);

  // merged gemm1 (routed + shared), then merged gemm2
  gemm1m_kernel<<<G1, 512, 0, stream>>>(xb, order, poff, w13r, b1, b3,
                                        w13s, bs1, bs3, h, hs);
  gemm2m_kernel<<<G2, 512, 0, stream>>>(h, hs, poff, w2b, b2, ws2b, bs2, yb, out);

  // out += routed combine (vectorized)
  combine4_kernel<<<T_TOK, 256, 0, stream>>>(out, yb, pos, top_w);
}